// Round 4
// baseline (847.333 us; speedup 1.0000x reference)
//
#include <hip/hip_runtime.h>

#define CH 128
#define PIXTOT (4*256*256)   // 262144

typedef unsigned short u16;
typedef short short8 __attribute__((ext_vector_type(8)));
typedef float f32x4 __attribute__((ext_vector_type(4)));

__device__ __forceinline__ float bf2f(u16 u){ return __uint_as_float(((unsigned)u)<<16); }
// fast bf16 round (half-up): 2 instrs, same 0.5-ulp max error as RNE
__device__ __forceinline__ u16 f2bf(float f){
  return (u16)((__float_as_uint(f) + 0x8000u) >> 16);
}
__device__ __forceinline__ float sigm(float x){ return 1.f/(1.f+__expf(-x)); }
__device__ __forceinline__ float tanh_f(float x){ return 1.f - 2.f/(__expf(2.f*x)+1.f); }

// ---------------------------------------------------------------------------
// Convert the three MFMA weight matrices fp32 -> bf16 (once per launch).
__global__ __launch_bounds__(256) void wcvt_kernel(
    const float* __restrict__ W0, const float* __restrict__ W1,
    const float* __restrict__ Wm,
    u16* __restrict__ W0b, u16* __restrict__ W1b, u16* __restrict__ Wmb)
{
  int i = blockIdx.x*256 + threadIdx.x;   // grid covers 131072
  W0b[i] = f2bf(W0[i]);
  W1b[i] = f2bf(W1[i]);
  if (i < 49152) Wmb[i] = f2bf(Wm[i]);
}

// ---------------------------------------------------------------------------
// U[b][i][o] = sum_f Wmsg[o,f]*nf[b,f,i] + bmsg[o]   (h_i part, bias folded)
// V[b][w][o] = sum_f Wmsg[o,128+f]*nf[b,f,w]         (h_w part)
__global__ __launch_bounds__(128) void uv_kernel(
    const float* __restrict__ nf, const float* __restrict__ Wmsg,
    const float* __restrict__ bmsg, float* __restrict__ U, float* __restrict__ V)
{
  int blk = blockIdx.x; int b = blk >> 8; int i = blk & 255;
  __shared__ float xs[128];
  int t = threadIdx.x;
  xs[t] = nf[((size_t)(b*CH + t))*256 + i];
  __syncthreads();
  float su = bmsg[t];
  float sv = 0.f;
  const float* w1 = Wmsg + (size_t)t*384;
  const float* w2 = w1 + 128;
  for (int f=0; f<128; f++){ float xf = xs[f]; su += w1[f]*xf; sv += w2[f]*xf; }
  U[((size_t)(b*256 + i))*CH + t] = su;
  V[((size_t)(b*256 + i))*CH + t] = sv;
}

// ---------------------------------------------------------------------------
// Stage edge tile (b, q1, w0..w0+31) x 128 ch into xs[pixel][channel] bf16.
// edge fp32 layout: [b][c][q1][w].
__device__ __forceinline__ void stage_edge32(
    const float* __restrict__ edge, int b, int q1, int w0, u16 (*xs)[136], int t)
{
  const int c = t >> 1, px0 = (t & 1) * 16;
  const float* src = edge + ((size_t)(b*CH + c)*256 + q1)*256 + w0 + px0;
  #pragma unroll
  for (int j=0; j<4; j++){
    f32x4 v = *(const f32x4*)(src + j*4);
    u16* dst = &xs[px0 + j*4][c];
    dst[0*136]=f2bf(v[0]); dst[1*136]=f2bf(v[1]);
    dst[2*136]=f2bf(v[2]); dst[3*136]=f2bf(v[3]);
  }
}

// ---------------------------------------------------------------------------
// One LSTM layer on a 32-pixel tile. Wave wv handles out-ch [wv*32, wv*32+32)
// for all 3 live gates (i rows 0..127, g 256..383, o 384..511; f dead, h0=0).
// x_out = sig(o)*tanh(sig(i)*tanh(g)).  acc = 3 g x 2 rs x 2 nt = 48 AGPRs.
__device__ __forceinline__ void lstm_layer32(
    const u16 (*xin)[136], u16 (*xout)[136],
    const u16* __restrict__ W, const float* __restrict__ Bv,
    int oc0, int lm, int quad)
{
  f32x4 acc[3][2][2];
  #pragma unroll
  for (int g=0; g<3; g++)
    #pragma unroll
    for (int rs=0; rs<2; rs++)
      #pragma unroll
      for (int nt=0; nt<2; nt++){ f32x4 z = {0.f,0.f,0.f,0.f}; acc[g][rs][nt] = z; }
  #pragma unroll
  for (int k0=0; k0<128; k0+=32){
    short8 bfr[2];
    #pragma unroll
    for (int nt=0; nt<2; nt++)
      bfr[nt] = *(const short8*)&xin[nt*16+lm][k0 + quad*8];
    #pragma unroll
    for (int g=0; g<3; g++){
      const int gb = (g==0)?0:((g==1)?256:384);
      #pragma unroll
      for (int rs=0; rs<2; rs++){
        const short8 afr = *(const short8*)(W + ((size_t)(gb + oc0 + rs*16 + lm))*256 + k0 + quad*8);
        #pragma unroll
        for (int nt=0; nt<2; nt++)
          acc[g][rs][nt] = __builtin_amdgcn_mfma_f32_16x16x32_bf16(afr, bfr[nt], acc[g][rs][nt], 0, 0, 0);
      }
    }
  }
  #pragma unroll
  for (int rs=0; rs<2; rs++){
    float bi[3][4];
    #pragma unroll
    for (int g=0; g<3; g++){
      const int gb = (g==0)?0:((g==1)?256:384);
      #pragma unroll
      for (int r=0; r<4; r++) bi[g][r] = Bv[gb + oc0 + rs*16 + quad*4 + r];
    }
    #pragma unroll
    for (int nt=0; nt<2; nt++){
      ushort4 w4;
      #pragma unroll
      for (int r=0; r<4; r++){
        float iv = acc[0][rs][nt][r] + bi[0][r];
        float gv = acc[1][rs][nt][r] + bi[1][r];
        float ov = acc[2][rs][nt][r] + bi[2][r];
        float cc = sigm(iv) * tanh_f(gv);
        float xv = sigm(ov) * tanh_f(cc);
        ((u16*)&w4)[r] = f2bf(xv);
      }
      *(ushort4*)&xout[nt*16+lm][oc0 + rs*16 + quad*4] = w4;
    }
  }
}

// ---------------------------------------------------------------------------
// Fused link rounds, 32-px tiles. MODE 0: input = edge tile.
// MODE 1: input = (Wmsg_e . edge + U + V) * A1   (m_pre recomputed, scaled).
// Writes Aout[Q=(b,q1,w)] = sigmoid(Wo . x2 + bo); MODE1 also scatters the
// final A output (outA[b][w][q1] = value).
template<int MODE>
__global__ __launch_bounds__(256, 4) void link_kernel(
    const float* __restrict__ edge, const float* __restrict__ A1,
    const float* __restrict__ U, const float* __restrict__ V,
    const u16* __restrict__ Wmb,
    const u16* __restrict__ W0, const float* __restrict__ B0,
    const u16* __restrict__ W1, const float* __restrict__ B1,
    const float* __restrict__ Wo, const float* __restrict__ Bo,
    float* __restrict__ Aout, float* __restrict__ outA)
{
  __shared__ u16 xs[32][136];
  __shared__ u16 ys[32][136];
  __shared__ float red[32][8];
  const int t = threadIdx.x;
  const int Q0 = blockIdx.x * 32;
  const int b = Q0 >> 16, q1 = (Q0 >> 8) & 255, w0 = Q0 & 255;
  stage_edge32(edge, b, q1, w0, xs, t);
  __syncthreads();
  const int wv = t >> 6, lane = t & 63, lm = lane & 15, quad = lane >> 4;
  const int oc0 = wv*32;
  if (MODE){
    f32x4 acc[2][2];
    #pragma unroll
    for (int rs=0; rs<2; rs++)
      #pragma unroll
      for (int nt=0; nt<2; nt++){ f32x4 z = {0.f,0.f,0.f,0.f}; acc[rs][nt] = z; }
    #pragma unroll
    for (int k0=0; k0<128; k0+=32){
      short8 bfr[2];
      #pragma unroll
      for (int nt=0; nt<2; nt++)
        bfr[nt] = *(const short8*)&xs[nt*16+lm][k0 + quad*8];
      #pragma unroll
      for (int rs=0; rs<2; rs++){
        const short8 afr = *(const short8*)(Wmb + ((size_t)(oc0 + rs*16 + lm))*384 + 256 + k0 + quad*8);
        #pragma unroll
        for (int nt=0; nt<2; nt++)
          acc[rs][nt] = __builtin_amdgcn_mfma_f32_16x16x32_bf16(afr, bfr[nt], acc[rs][nt], 0, 0, 0);
      }
    }
    #pragma unroll
    for (int rs=0; rs<2; rs++){
      const int o0 = oc0 + rs*16 + quad*4;
      const f32x4 ug = *(const f32x4*)(U + ((size_t)(b*256 + q1))*CH + o0);
      #pragma unroll
      for (int nt=0; nt<2; nt++){
        const int px = nt*16 + lm;
        const float a1 = A1[Q0 + px];
        const f32x4 vg = *(const f32x4*)(V + ((size_t)(b*256 + w0 + px))*CH + o0);
        ushort4 w4;
        #pragma unroll
        for (int r=0; r<4; r++)
          ((u16*)&w4)[r] = f2bf((acc[rs][nt][r] + ug[r] + vg[r]) * a1);
        *(ushort4*)&ys[px][o0] = w4;
      }
    }
    __syncthreads();
  }
  u16 (*in0)[136] = MODE ? ys : xs;
  u16 (*tmp)[136] = MODE ? xs : ys;
  lstm_layer32((const u16(*)[136])in0, tmp, W0, B0, oc0, lm, quad);
  __syncthreads();
  lstm_layer32((const u16(*)[136])tmp, in0, W1, B1, oc0, lm, quad);
  __syncthreads();
  {
    int p = t >> 3, part = t & 7;
    float s = 0.f;
    #pragma unroll
    for (int j=0; j<16; j+=4){
      const f32x4 wv4 = *(const f32x4*)(Wo + part*16 + j);
      #pragma unroll
      for (int e2=0; e2<4; e2++) s += bf2f(in0[p][part*16 + j + e2]) * wv4[e2];
    }
    red[p][part] = s;
  }
  __syncthreads();
  if (t < 32){
    float a = Bo[0];
    #pragma unroll
    for (int k=0; k<8; k++) a += red[t][k];
    const float sg = sigm(a);
    Aout[Q0 + t] = sg;
    if (MODE)
      outA[(size_t)b*65536 + (size_t)(w0 + t)*256 + q1] = sg;
  }
}

// ---------------------------------------------------------------------------
// msum[b][q1][o] = sum_w (Wmsg_e.e[b,:,q1,w] + U[b,q1,:] + V[b,w,:])[o] * A2[b,q1,w]
// A2[b,q1,w] = A2T[b][w][q1].  One block per (b,q1); 8 w-tiles of 32 px.
__global__ __launch_bounds__(256, 4) void ksum_kernel(
    const float* __restrict__ edge, const float* __restrict__ A2T,
    const float* __restrict__ U, const float* __restrict__ V,
    const u16* __restrict__ Wmb, float* __restrict__ msum)
{
  __shared__ u16 xs[32][136];
  __shared__ float a2s[32];
  __shared__ float sb[16][132];
  const int t = threadIdx.x;
  const int b = blockIdx.x >> 8, q1 = blockIdx.x & 255;
  const int wv = t >> 6, lane = t & 63, lm = lane & 15, quad = lane >> 4;
  const int oc0 = wv*32;
  f32x4 sAcc[2];
  #pragma unroll
  for (int rs=0; rs<2; rs++){ f32x4 z = {0.f,0.f,0.f,0.f}; sAcc[rs] = z; }
  f32x4 ug[2];
  #pragma unroll
  for (int rs=0; rs<2; rs++)
    ug[rs] = *(const f32x4*)(U + ((size_t)(b*256 + q1))*CH + oc0 + rs*16 + quad*4);

  for (int w0=0; w0<256; w0+=32){
    __syncthreads();
    stage_edge32(edge, b, q1, w0, xs, t);
    if (t < 32) a2s[t] = A2T[(size_t)b*65536 + (size_t)(w0 + t)*256 + q1];
    __syncthreads();
    f32x4 acc[2][2];
    #pragma unroll
    for (int rs=0; rs<2; rs++)
      #pragma unroll
      for (int nt=0; nt<2; nt++){ f32x4 z = {0.f,0.f,0.f,0.f}; acc[rs][nt] = z; }
    #pragma unroll
    for (int k0=0; k0<128; k0+=32){
      short8 bfr[2];
      #pragma unroll
      for (int nt=0; nt<2; nt++)
        bfr[nt] = *(const short8*)&xs[nt*16+lm][k0 + quad*8];
      #pragma unroll
      for (int rs=0; rs<2; rs++){
        const short8 afr = *(const short8*)(Wmb + ((size_t)(oc0 + rs*16 + lm))*384 + 256 + k0 + quad*8);
        #pragma unroll
        for (int nt=0; nt<2; nt++)
          acc[rs][nt] = __builtin_amdgcn_mfma_f32_16x16x32_bf16(afr, bfr[nt], acc[rs][nt], 0, 0, 0);
      }
    }
    #pragma unroll
    for (int rs=0; rs<2; rs++){
      const int o0 = oc0 + rs*16 + quad*4;
      #pragma unroll
      for (int nt=0; nt<2; nt++){
        const int px = nt*16 + lm;
        const float a2 = a2s[px];
        const f32x4 vg = *(const f32x4*)(V + ((size_t)(b*256 + w0 + px))*CH + o0);
        #pragma unroll
        for (int r=0; r<4; r++)
          sAcc[rs][r] += (acc[rs][nt][r] + ug[rs][r] + vg[r]) * a2;
      }
    }
  }
  #pragma unroll
  for (int rs=0; rs<2; rs++){
    const int o0 = oc0 + rs*16 + quad*4;
    #pragma unroll
    for (int r=0; r<4; r++) sb[lm][o0 + r] = sAcc[rs][r];
  }
  __syncthreads();
  if (t < 128){
    float s = 0.f;
    #pragma unroll
    for (int l=0; l<16; l++) s += sb[l][t];
    msum[((size_t)(b*256 + q1))*CH + t] = s;
  }
}

// ---------------------------------------------------------------------------
// GRU (set 0 for node 0, else set 1) + fc_soft_max readout + pred assembly.
__global__ __launch_bounds__(128) void k5_kernel(
    const float* __restrict__ msum, const float* __restrict__ nf,
    const float* __restrict__ Wih0, const float* __restrict__ Whh0,
    const float* __restrict__ bih0, const float* __restrict__ bhh0,
    const float* __restrict__ Wih1, const float* __restrict__ Whh1,
    const float* __restrict__ bih1, const float* __restrict__ bhh1,
    const float* __restrict__ Wr0, const float* __restrict__ br0,
    const float* __restrict__ Wr1, const float* __restrict__ br1,
    float* __restrict__ outp)
{
  const int blk = blockIdx.x, b = blk >> 8, n = blk & 255;
  __shared__ float xsh[128], hsh[128], hnew[128], lg[16];
  const int t = threadIdx.x;
  xsh[t] = msum[((size_t)(b*256 + n))*CH + t];
  hsh[t] = nf[((size_t)(b*CH + t))*256 + n];
  __syncthreads();
  const float* Wih = n ? Wih1 : Wih0;  const float* Whh = n ? Whh1 : Whh0;
  const float* bih = n ? bih1 : bih0;  const float* bhh = n ? bhh1 : bhh0;
  float gi[3], gh[3];
  #pragma unroll
  for (int prt=0; prt<3; prt++){
    int row = prt*128 + t;
    const float* wi_ = Wih + (size_t)row*CH;
    const float* wh_ = Whh + (size_t)row*CH;
    float si = 0.f, sh2 = 0.f;
    for (int k=0; k<128; k+=4){
      f32x4 wv1 = *(const f32x4*)(wi_ + k);
      f32x4 wv2 = *(const f32x4*)(wh_ + k);
      #pragma unroll
      for (int j=0; j<4; j++){ si += wv1[j]*xsh[k+j]; sh2 += wv2[j]*hsh[k+j]; }
    }
    gi[prt] = si + bih[row];
    gh[prt] = sh2 + bhh[row];
  }
  float r  = sigm(gi[0] + gh[0]);
  float z  = sigm(gi[1] + gh[1]);
  float ng = tanh_f(gi[2] + r*gh[2]);
  hnew[t] = (1.f - z)*ng + z*hsh[t];
  __syncthreads();
  const int K = n ? 12 : 10;
  const float* Wr = n ? Wr1 : Wr0;  const float* br = n ? br1 : br0;
  if (t < K){
    const float* wr_ = Wr + (size_t)t*CH;
    float s = 0.f;
    for (int k=0; k<128; k+=4){
      f32x4 wv1 = *(const f32x4*)(wr_ + k);
      #pragma unroll
      for (int j=0; j<4; j++) s += wv1[j]*hnew[k+j];
    }
    lg[t] = s + br[t];
  }
  __syncthreads();
  if (t < 12){
    float o = 0.f;
    if (t < K){
      float mx = -1e30f;
      for (int j=0; j<K; j++) mx = fmaxf(mx, lg[j]);
      float se = 0.f;
      for (int j=0; j<K; j++) se += __expf(lg[j] - mx);
      o = lg[t] - mx - __logf(se);
    }
    outp[((size_t)(b*256 + n))*12 + t] = o;
  }
}

// ---------------------------------------------------------------------------
extern "C" void kernel_launch(void* const* d_in, const int* in_sizes, int n_in,
                              void* d_out, int out_size, void* d_ws, size_t ws_size,
                              hipStream_t stream)
{
  (void)in_sizes; (void)n_in; (void)out_size; (void)ws_size;
  const float* edge = (const float*)d_in[0];
  const float* nf   = (const float*)d_in[1];
  const float* Wl0  = (const float*)d_in[5];
  const float* bl0  = (const float*)d_in[6];
  const float* Wl1  = (const float*)d_in[7];
  const float* bl1  = (const float*)d_in[8];
  const float* Wlo  = (const float*)d_in[9];
  const float* blo  = (const float*)d_in[10];
  const float* Wmsg = (const float*)d_in[11];
  const float* bmsg = (const float*)d_in[12];
  const float* Wih0 = (const float*)d_in[13];
  const float* Whh0 = (const float*)d_in[14];
  const float* bih0 = (const float*)d_in[15];
  const float* bhh0 = (const float*)d_in[16];
  const float* Wih1 = (const float*)d_in[17];
  const float* Whh1 = (const float*)d_in[18];
  const float* bih1 = (const float*)d_in[19];
  const float* bhh1 = (const float*)d_in[20];
  const float* Wr0  = (const float*)d_in[21];
  const float* br0  = (const float*)d_in[22];
  const float* Wr1  = (const float*)d_in[23];
  const float* br1  = (const float*)d_in[24];

  char* ws = (char*)d_ws;
  float* A1v  = (float*)(ws);                        // 1 MB
  float* A2T  = (float*)(ws + 1048576);              // 1 MB
  float* U    = (float*)(ws + 2097152);              // 512 KB
  float* V    = (float*)(ws + 2621440);              // 512 KB
  float* msum = (float*)(ws + 3145728);              // 512 KB
  u16*   W0b  = (u16*)(ws + 3670016);                // 256 KB (512x256 bf16)
  u16*   W1b  = (u16*)(ws + 3932160);                // 256 KB
  u16*   Wmb  = (u16*)(ws + 4194304);                // 96 KB (128x384 bf16)
                                                     // total ~4.3 MB
  float* outA = (float*)d_out;
  float* outP = outA + (size_t)PIXTOT;

  wcvt_kernel<<<dim3(512), dim3(256), 0, stream>>>(Wl0, Wl1, Wmsg, W0b, W1b, Wmb);
  uv_kernel<<<dim3(4*256), dim3(128), 0, stream>>>(nf, Wmsg, bmsg, U, V);
  link_kernel<0><<<dim3(PIXTOT/32), dim3(256), 0, stream>>>(
      edge, (const float*)nullptr, U, V, Wmb, W0b, bl0, W1b, bl1, Wlo, blo,
      A1v, (float*)nullptr);
  link_kernel<1><<<dim3(PIXTOT/32), dim3(256), 0, stream>>>(
      edge, A1v, U, V, Wmb, W0b, bl0, W1b, bl1, Wlo, blo, A2T, outA);
  ksum_kernel<<<dim3(4*256), dim3(256), 0, stream>>>(edge, A2T, U, V, Wmb, msum);
  k5_kernel<<<dim3(4*256), dim3(128), 0, stream>>>(
      msum, nf, Wih0, Whh0, bih0, bhh0, Wih1, Whh1, bih1, bhh1,
      Wr0, br0, Wr1, br1, outP);
}

// Round 6
// 639.205 us; speedup vs baseline: 1.3256x; 1.3256x over previous
//
#include <hip/hip_runtime.h>

#define CH 128
#define PIXTOT (4*256*256)   // 262144
#define L2E 1.4426950408889634f

typedef unsigned short u16;
typedef short short8 __attribute__((ext_vector_type(8)));
typedef float f32x4 __attribute__((ext_vector_type(4)));

__device__ __forceinline__ float bf2f(u16 u){ return __uint_as_float(((unsigned)u)<<16); }
__device__ __forceinline__ u16 f2bf(float f){
  return (u16)((__float_as_uint(f) + 0x8000u) >> 16);
}
__device__ __forceinline__ float fexp2(float x){ return __builtin_amdgcn_exp2f(x); }
__device__ __forceinline__ float frcp(float x){ return __builtin_amdgcn_rcpf(x); }
__device__ __forceinline__ float sigm(float x){ return frcp(1.f + fexp2(-L2E*x)); }
__device__ __forceinline__ float tanh_f(float x){ return 1.f - 2.f*frcp(fexp2(2.f*L2E*x)+1.f); }

// ---------------------------------------------------------------------------
// Weight prep (once per launch):
//  - W0c/W1c [384][128] bf16: live LSTM gate rows (i,g,o; f dead since c0=0),
//    K-cols 0..127 (h0=0), pre-scaled by (-log2e, 2log2e, -log2e) so the
//    epilogue uses bare v_exp (exp2).
//  - b0c/b1c [384] fp32 scaled the same way.
//  - Wmc [128][128] bf16: Wmsg e-part (cols 256..383), unscaled.
__global__ __launch_bounds__(256) void wcvt_kernel(
    const float* __restrict__ W0, const float* __restrict__ bl0,
    const float* __restrict__ W1, const float* __restrict__ bl1,
    const float* __restrict__ Wm,
    u16* __restrict__ W0c, u16* __restrict__ W1c,
    float* __restrict__ b0c, float* __restrict__ b1c,
    u16* __restrict__ Wmc)
{
  int idx = blockIdx.x*256 + threadIdx.x;   // grid covers 49152
  int row = idx >> 7, col = idx & 127;
  int slot = row >> 7;
  int src = (row < 128) ? row : row + 128;  // i:0..127, g:256..383, o:384..511
  float s = (slot == 1) ? (2.f*L2E) : (-L2E);
  W0c[idx] = f2bf(W0[(size_t)src*256 + col] * s);
  W1c[idx] = f2bf(W1[(size_t)src*256 + col] * s);
  if (idx < 16384)
    Wmc[idx] = f2bf(Wm[(size_t)(idx>>7)*384 + 256 + (idx&127)]);
  if (idx < 384){
    b0c[idx] = bl0[src] * s;
    b1c[idx] = bl1[src] * s;
  }
}

// ---------------------------------------------------------------------------
// U[b][i][o] = sum_f Wmsg[o,f]*nf[b,f,i] + bmsg[o]   (h_i part, bias folded)
// V[b][w][o] = sum_f Wmsg[o,128+f]*nf[b,f,w]         (h_w part)
__global__ __launch_bounds__(128) void uv_kernel(
    const float* __restrict__ nf, const float* __restrict__ Wmsg,
    const float* __restrict__ bmsg, float* __restrict__ U, float* __restrict__ V)
{
  int blk = blockIdx.x; int b = blk >> 8; int i = blk & 255;
  __shared__ float xs[128];
  int t = threadIdx.x;
  xs[t] = nf[((size_t)(b*CH + t))*256 + i];
  __syncthreads();
  float su = bmsg[t];
  float sv = 0.f;
  const float* w1 = Wmsg + (size_t)t*384;
  const float* w2 = w1 + 128;
  for (int f=0; f<128; f++){ float xf = xs[f]; su += w1[f]*xf; sv += w2[f]*xf; }
  U[((size_t)(b*256 + i))*CH + t] = su;
  V[((size_t)(b*256 + i))*CH + t] = sv;
}

// ---------------------------------------------------------------------------
// Stage edge tile (b, q1, w0..w0+63) x 128 ch into xs[pixel][channel] bf16.
__device__ __forceinline__ void stage_edge(
    const float* __restrict__ edge, int b, int q1, int w0, u16 (*xs)[136], int t)
{
  const int c = t >> 1, ph = (t & 1) * 32;
  const float* src = edge + ((size_t)(b*CH + c)*256 + q1)*256 + w0 + ph;
  #pragma unroll
  for (int j=0; j<8; j++){
    f32x4 v = *(const f32x4*)(src + j*4);
    u16* dst = &xs[ph + j*4][c];
    dst[0*136]=f2bf(v[0]); dst[1*136]=f2bf(v[1]);
    dst[2*136]=f2bf(v[2]); dst[3*136]=f2bf(v[3]);
  }
}

// ---------------------------------------------------------------------------
// One LSTM layer on a 64-pixel tile. Gates pre-scaled so a=exp2(iv)=e^-i,
// b=exp2(gv)=e^{2g}, f=exp2(ov)=e^-o.
//   c  = sig(i)*tanh(g) = (b-1)/((1+a)(b+1)),  |c|<1
//   x  = tanh(c)*sig(o) = c*(945+105c^2+c^4) / ((945+420c^2+15c^4)*(1+f))
// LAST=false: write bf16 x to xout.  LAST=true: accumulate Wo-dot partials.
template<bool LAST>
__device__ __forceinline__ void lstm_layer(
    const u16 (*xin)[136], u16 (*xout)[136],
    const u16* __restrict__ W, const float* __restrict__ Bc,
    int oc0, int lm, int quad, const float woc[2][4], float* partial)
{
  f32x4 acc[3][2][4];
  #pragma unroll
  for (int g=0; g<3; g++)
    #pragma unroll
    for (int rs=0; rs<2; rs++)
      #pragma unroll
      for (int nt=0; nt<4; nt++){ f32x4 z = {0.f,0.f,0.f,0.f}; acc[g][rs][nt] = z; }
  #pragma unroll
  for (int k0=0; k0<128; k0+=32){
    short8 bfr[4];
    #pragma unroll
    for (int nt=0; nt<4; nt++)
      bfr[nt] = *(const short8*)&xin[nt*16+lm][k0 + quad*8];
    #pragma unroll
    for (int g=0; g<3; g++){
      #pragma unroll
      for (int rs=0; rs<2; rs++){
        const short8 afr = *(const short8*)(W + ((size_t)(g*128 + oc0 + rs*16 + lm))*128 + k0 + quad*8);
        #pragma unroll
        for (int nt=0; nt<4; nt++)
          acc[g][rs][nt] = __builtin_amdgcn_mfma_f32_16x16x32_bf16(afr, bfr[nt], acc[g][rs][nt], 0, 0, 0);
      }
    }
  }
  #pragma unroll
  for (int rs=0; rs<2; rs++){
    float bi[3][4];
    #pragma unroll
    for (int g=0; g<3; g++)
      #pragma unroll
      for (int r=0; r<4; r++) bi[g][r] = Bc[g*128 + oc0 + rs*16 + quad*4 + r];
    #pragma unroll
    for (int nt=0; nt<4; nt++){
      ushort4 w4;
      #pragma unroll
      for (int r=0; r<4; r++){
        float iv = acc[0][rs][nt][r] + bi[0][r];
        float gv = fminf(acc[1][rs][nt][r] + bi[1][r], 80.f);  // guard e^{2g} ovf
        float ov = acc[2][rs][nt][r] + bi[2][r];
        float a  = fexp2(iv);
        float bb = fexp2(gv);
        float f  = fexp2(ov);
        float c  = (bb - 1.f) * frcp((1.f + a) * (bb + 1.f));
        float c2 = c*c, c4 = c2*c2;
        float p  = __builtin_fmaf(c2, 105.f, 945.f) + c4;
        float q  = __builtin_fmaf(c4, 15.f, __builtin_fmaf(c2, 420.f, 945.f));
        float xo = c * p * frcp(q * (1.f + f));
        if (LAST) partial[nt] = __builtin_fmaf(xo, woc[rs][r], partial[nt]);
        else      ((u16*)&w4)[r] = f2bf(xo);
      }
      if (!LAST)
        *(ushort4*)&xout[nt*16+lm][oc0 + rs*16 + quad*4] = w4;
    }
  }
}

// ---------------------------------------------------------------------------
// Fused link rounds, 64-px tiles. MODE 0: input = edge tile.
// MODE 1: input = (Wmsg_e . edge + U + V) * A1.
// Aout[Q=(b,q1,w)] = sigmoid(Wo.x2 + bo); MODE1 also scatters final A output
// and its natural-layout copy A2nat[b][v][w].
template<int MODE>
__global__ __launch_bounds__(256, 2) void link_kernel(
    const float* __restrict__ edge, const float* __restrict__ A1,
    const float* __restrict__ U, const float* __restrict__ V,
    const u16* __restrict__ Wmc,
    const u16* __restrict__ W0c, const float* __restrict__ B0c,
    const u16* __restrict__ W1c, const float* __restrict__ B1c,
    const float* __restrict__ Wo, const float* __restrict__ Bo,
    float* __restrict__ Aout, float* __restrict__ outA, float* __restrict__ A2nat)
{
  __shared__ u16 xs[64][136];
  __shared__ u16 ys[64][136];
  __shared__ float red[64][17];
  const int t = threadIdx.x;
  const int Q0 = blockIdx.x * 64;
  const int b = Q0 >> 16, q1 = (Q0 >> 8) & 255, w0 = Q0 & 255;
  stage_edge(edge, b, q1, w0, xs, t);
  const int wv = t >> 6, lane = t & 63, lm = lane & 15, quad = lane >> 4;
  const int oc0 = wv*32;
  float woc[2][4];
  #pragma unroll
  for (int rs=0; rs<2; rs++){
    const f32x4 wv4 = *(const f32x4*)(Wo + oc0 + rs*16 + quad*4);
    #pragma unroll
    for (int r=0; r<4; r++) woc[rs][r] = wv4[r];
  }
  __syncthreads();
  if (MODE){
    f32x4 acc[2][4];
    #pragma unroll
    for (int rs=0; rs<2; rs++)
      #pragma unroll
      for (int nt=0; nt<4; nt++){ f32x4 z = {0.f,0.f,0.f,0.f}; acc[rs][nt] = z; }
    #pragma unroll
    for (int k0=0; k0<128; k0+=32){
      short8 bfr[4];
      #pragma unroll
      for (int nt=0; nt<4; nt++)
        bfr[nt] = *(const short8*)&xs[nt*16+lm][k0 + quad*8];
      #pragma unroll
      for (int rs=0; rs<2; rs++){
        const short8 afr = *(const short8*)(Wmc + ((size_t)(oc0 + rs*16 + lm))*128 + k0 + quad*8);
        #pragma unroll
        for (int nt=0; nt<4; nt++)
          acc[rs][nt] = __builtin_amdgcn_mfma_f32_16x16x32_bf16(afr, bfr[nt], acc[rs][nt], 0, 0, 0);
      }
    }
    #pragma unroll
    for (int rs=0; rs<2; rs++){
      const int o0 = oc0 + rs*16 + quad*4;
      const f32x4 ug = *(const f32x4*)(U + ((size_t)(b*256 + q1))*CH + o0);
      #pragma unroll
      for (int nt=0; nt<4; nt++){
        const int px = nt*16 + lm;
        const float a1 = A1[Q0 + px];
        const f32x4 vg = *(const f32x4*)(V + ((size_t)(b*256 + w0 + px))*CH + o0);
        ushort4 w4;
        #pragma unroll
        for (int r=0; r<4; r++)
          ((u16*)&w4)[r] = f2bf((acc[rs][nt][r] + ug[r] + vg[r]) * a1);
        *(ushort4*)&ys[px][o0] = w4;
      }
    }
    __syncthreads();
  }
  const u16 (*in0)[136] = MODE ? (const u16(*)[136])ys : (const u16(*)[136])xs;
  u16 (*buf)[136] = MODE ? xs : ys;
  float partial[4] = {0.f, 0.f, 0.f, 0.f};
  lstm_layer<false>(in0, buf, W0c, B0c, oc0, lm, quad, woc, partial);
  __syncthreads();
  lstm_layer<true>((const u16(*)[136])buf, (u16(*)[136])nullptr, W1c, B1c, oc0, lm, quad, woc, partial);
  #pragma unroll
  for (int nt=0; nt<4; nt++) red[nt*16+lm][wv*4+quad] = partial[nt];
  __syncthreads();
  if (t < 64){
    float s = Bo[0];
    #pragma unroll
    for (int k=0; k<16; k++) s += red[t][k];
    const float sg = sigm(s);
    Aout[Q0 + t] = sg;
    if (MODE){
      const size_t p = (size_t)b*65536 + (size_t)(w0 + t)*256 + q1;
      outA[p]  = sg;
      A2nat[p] = sg;
    }
  }
}

// ---------------------------------------------------------------------------
// Weighted edge row-sum: s_e[b,i,c] = sum_w e[b,c,i,w] * A2nat[b,i,w]
// and sA[b,i] = sum_w A2nat[b,i,w].
__global__ __launch_bounds__(256) void se_kernel(
    const float* __restrict__ edge, const float* __restrict__ A2nat,
    float* __restrict__ s_e, float* __restrict__ sA)
{
  const int b = blockIdx.x >> 8, i = blockIdx.x & 255;
  __shared__ float al[256];
  __shared__ float sb[2][128];
  __shared__ float rr[64];
  const int t = threadIdx.x;
  al[t] = A2nat[((size_t)(b*256 + i))*256 + t];
  __syncthreads();
  const int c = t & 127, half = t >> 7;
  const float* src = edge + (((size_t)(b*CH + c))*256 + i)*256 + half*128;
  float s = 0.f;
  #pragma unroll
  for (int j=0; j<32; j++){
    const f32x4 v = *(const f32x4*)(src + j*4);
    const float* ap = &al[half*128 + j*4];
    s += v[0]*ap[0] + v[1]*ap[1] + v[2]*ap[2] + v[3]*ap[3];
  }
  sb[half][c] = s;
  if (t < 64) rr[t] = al[t] + al[t+64] + al[t+128] + al[t+192];
  __syncthreads();
  if (t < 128) s_e[((size_t)(b*256 + i))*CH + t] = sb[0][t] + sb[1][t];
  if (t == 0){
    float sa = 0.f;
    for (int k=0; k<64; k++) sa += rr[k];
    sA[b*256 + i] = sa;
  }
}

// ---------------------------------------------------------------------------
// msum[b,i,o] = W3[o,:].s_e[b,i,:] + U[b,i,o]*sA[b,i] + sum_w A2nat[b,i,w]*V[b,w,o]
__global__ __launch_bounds__(128) void mfinal_kernel(
    const float* __restrict__ s_e, const float* __restrict__ sA,
    const float* __restrict__ A2nat, const float* __restrict__ V,
    const float* __restrict__ Wmsg, const float* __restrict__ U,
    float* __restrict__ msum)
{
  const int b = blockIdx.x >> 8, i = blockIdx.x & 255;
  __shared__ float se_s[128];
  __shared__ float al[256];
  const int t = threadIdx.x;
  se_s[t] = s_e[((size_t)(b*256 + i))*CH + t];
  al[t]       = A2nat[((size_t)(b*256 + i))*256 + t];
  al[t + 128] = A2nat[((size_t)(b*256 + i))*256 + t + 128];
  __syncthreads();
  const float* w3 = Wmsg + (size_t)t*384 + 256;
  float s = U[((size_t)(b*256 + i))*CH + t] * sA[b*256 + i];
  #pragma unroll 4
  for (int k=0; k<128; k+=4){
    const f32x4 wv4 = *(const f32x4*)(w3 + k);
    s += wv4[0]*se_s[k] + wv4[1]*se_s[k+1] + wv4[2]*se_s[k+2] + wv4[3]*se_s[k+3];
  }
  const float* vp = V + ((size_t)(b*256))*CH + t;
  #pragma unroll 8
  for (int w=0; w<256; w++)
    s += al[w] * vp[(size_t)w*CH];
  msum[((size_t)(b*256 + i))*CH + t] = s;
}

// ---------------------------------------------------------------------------
// GRU (set 0 for node 0, else set 1) + fc_soft_max readout + pred assembly.
__global__ __launch_bounds__(128) void k5_kernel(
    const float* __restrict__ msum, const float* __restrict__ nf,
    const float* __restrict__ Wih0, const float* __restrict__ Whh0,
    const float* __restrict__ bih0, const float* __restrict__ bhh0,
    const float* __restrict__ Wih1, const float* __restrict__ Whh1,
    const float* __restrict__ bih1, const float* __restrict__ bhh1,
    const float* __restrict__ Wr0, const float* __restrict__ br0,
    const float* __restrict__ Wr1, const float* __restrict__ br1,
    float* __restrict__ outp)
{
  const int blk = blockIdx.x, b = blk >> 8, n = blk & 255;
  __shared__ float xsh[128], hsh[128], hnew[128], lg[16];
  const int t = threadIdx.x;
  xsh[t] = msum[((size_t)(b*256 + n))*CH + t];
  hsh[t] = nf[((size_t)(b*CH + t))*256 + n];
  __syncthreads();
  const float* Wih = n ? Wih1 : Wih0;  const float* Whh = n ? Whh1 : Whh0;
  const float* bih = n ? bih1 : bih0;  const float* bhh = n ? bhh1 : bhh0;
  float gi[3], gh[3];
  #pragma unroll
  for (int prt=0; prt<3; prt++){
    int row = prt*128 + t;
    const float* wi_ = Wih + (size_t)row*CH;
    const float* wh_ = Whh + (size_t)row*CH;
    float si = 0.f, sh2 = 0.f;
    for (int k=0; k<128; k+=4){
      f32x4 wv1 = *(const f32x4*)(wi_ + k);
      f32x4 wv2 = *(const f32x4*)(wh_ + k);
      #pragma unroll
      for (int j=0; j<4; j++){ si += wv1[j]*xsh[k+j]; sh2 += wv2[j]*hsh[k+j]; }
    }
    gi[prt] = si + bih[row];
    gh[prt] = sh2 + bhh[row];
  }
  float r  = sigm(gi[0] + gh[0]);
  float z  = sigm(gi[1] + gh[1]);
  float ng = tanh_f(gi[2] + r*gh[2]);
  hnew[t] = (1.f - z)*ng + z*hsh[t];
  __syncthreads();
  const int K = n ? 12 : 10;
  const float* Wr = n ? Wr1 : Wr0;  const float* br = n ? br1 : br0;
  if (t < K){
    const float* wr_ = Wr + (size_t)t*CH;
    float s = 0.f;
    for (int k=0; k<128; k+=4){
      f32x4 wv1 = *(const f32x4*)(wr_ + k);
      #pragma unroll
      for (int j=0; j<4; j++) s += wv1[j]*hnew[k+j];
    }
    lg[t] = s + br[t];
  }
  __syncthreads();
  if (t < 12){
    float o = 0.f;
    if (t < K){
      float mx = -1e30f;
      for (int j=0; j<K; j++) mx = fmaxf(mx, lg[j]);
      float se = 0.f;
      for (int j=0; j<K; j++) se += __expf(lg[j] - mx);
      o = lg[t] - mx - __logf(se);
    }
    outp[((size_t)(b*256 + n))*12 + t] = o;
  }
}

// ---------------------------------------------------------------------------
extern "C" void kernel_launch(void* const* d_in, const int* in_sizes, int n_in,
                              void* d_out, int out_size, void* d_ws, size_t ws_size,
                              hipStream_t stream)
{
  (void)in_sizes; (void)n_in; (void)out_size; (void)ws_size;
  const float* edge = (const float*)d_in[0];
  const float* nf   = (const float*)d_in[1];
  const float* Wl0  = (const float*)d_in[5];
  const float* bl0  = (const float*)d_in[6];
  const float* Wl1  = (const float*)d_in[7];
  const float* bl1  = (const float*)d_in[8];
  const float* Wlo  = (const float*)d_in[9];
  const float* blo  = (const float*)d_in[10];
  const float* Wmsg = (const float*)d_in[11];
  const float* bmsg = (const float*)d_in[12];
  const float* Wih0 = (const float*)d_in[13];
  const float* Whh0 = (const float*)d_in[14];
  const float* bih0 = (const float*)d_in[15];
  const float* bhh0 = (const float*)d_in[16];
  const float* Wih1 = (const float*)d_in[17];
  const float* Whh1 = (const float*)d_in[18];
  const float* bih1 = (const float*)d_in[19];
  const float* bhh1 = (const float*)d_in[20];
  const float* Wr0  = (const float*)d_in[21];
  const float* br0  = (const float*)d_in[22];
  const float* Wr1  = (const float*)d_in[23];
  const float* br1  = (const float*)d_in[24];

  // Workspace layout (fixed round-5 overlap bug: 512 KB = 524288, not 512000)
  char* ws = (char*)d_ws;
  float* A1v   = (float*)(ws);                       // [0,       1048576)
  float* A2nat = (float*)(ws + 1048576);             // [1048576, 2097152)
  float* U     = (float*)(ws + 2097152);             // [2097152, 2621440)
  float* V     = (float*)(ws + 2621440);             // [2621440, 3145728)
  float* msum  = (float*)(ws + 3145728);             // [3145728, 3670016)
  float* s_e   = (float*)(ws + 3670016);             // [3670016, 4194304)
  float* sAr   = (float*)(ws + 4194304);             // [4194304, 4198400)
  u16*   W0c   = (u16*)(ws + 4198400);               // [4198400, 4296704)
  u16*   W1c   = (u16*)(ws + 4296704);               // [4296704, 4395008)
  u16*   Wmc   = (u16*)(ws + 4395008);               // [4395008, 4427776)
  float* b0c   = (float*)(ws + 4427776);             // [4427776, 4429312)
  float* b1c   = (float*)(ws + 4429312);             // [4429312, 4430848)

  float* outA = (float*)d_out;
  float* outP = outA + (size_t)PIXTOT;

  wcvt_kernel<<<dim3(192), dim3(256), 0, stream>>>(
      Wl0, bl0, Wl1, bl1, Wmsg, W0c, W1c, b0c, b1c, Wmc);
  uv_kernel<<<dim3(4*256), dim3(128), 0, stream>>>(nf, Wmsg, bmsg, U, V);
  link_kernel<0><<<dim3(PIXTOT/64), dim3(256), 0, stream>>>(
      edge, (const float*)nullptr, U, V, Wmc, W0c, b0c, W1c, b1c, Wlo, blo,
      A1v, (float*)nullptr, (float*)nullptr);
  link_kernel<1><<<dim3(PIXTOT/64), dim3(256), 0, stream>>>(
      edge, A1v, U, V, Wmc, W0c, b0c, W1c, b1c, Wlo, blo,
      A1v, outA, A2nat);
  se_kernel<<<dim3(4*256), dim3(256), 0, stream>>>(edge, A2nat, s_e, sAr);
  mfinal_kernel<<<dim3(4*256), dim3(128), 0, stream>>>(
      s_e, sAr, A2nat, V, Wmsg, U, msum);
  k5_kernel<<<dim3(4*256), dim3(128), 0, stream>>>(
      msum, nf, Wih0, Whh0, bih0, bhh0, Wih1, Whh1, bih1, bhh1,
      Wr0, br0, Wr1, br1, outP);
}